// Round 1
// baseline (148.904 us; speedup 1.0000x reference)
//
#include <hip/hip_runtime.h>

#define TILE 256
#define N_SPLIT 8

__global__ void ol_init_ws(double* ws) {
    ws[0] = 0.0;  // sum iou_pen * mask
    ws[1] = 0.0;  // sum repel_pen^2 * mask
    ws[2] = 0.0;  // sum mask (pair count)
}

__global__ __launch_bounds__(256) void ol_pair_kernel(
    const float* __restrict__ pos, const float* __restrict__ size,
    const float* __restrict__ valid, double* __restrict__ ws, int n)
{
    __shared__ float4 sh_box[TILE];   // l, r, b, t
    __shared__ float4 sh_aux[TILE];   // x, y, area, valid

    const float EPSf = 1e-6f;
    const float RM   = 0.06f;

    int i = blockIdx.x * TILE + (int)threadIdx.x;

    // Load this thread's box once.
    float xi = 0.f, yi = 0.f, li = 0.f, ri = 0.f, bi = 0.f, ti = 0.f, ai = 0.f, vi = 0.f;
    if (i < n) {
        xi = pos[2 * i];
        yi = pos[2 * i + 1];
        float wi = size[2 * i];
        float hi = size[2 * i + 1];
        li = xi - 0.5f * wi;  ri = xi + 0.5f * wi;
        bi = yi - 0.5f * hi;  ti = yi + 0.5f * hi;
        ai = wi * hi;
        vi = valid[i];
    }

    float s_iou = 0.f, s_rep = 0.f, s_msk = 0.f;

    int ntiles = (n + TILE - 1) / TILE;
    for (int jt = blockIdx.y; jt < ntiles; jt += gridDim.y) {
        int jbase = jt * TILE;
        int j = jbase + (int)threadIdx.x;
        if (j < n) {
            float xj = pos[2 * j];
            float yj = pos[2 * j + 1];
            float wj = size[2 * j];
            float hj = size[2 * j + 1];
            sh_box[threadIdx.x] = make_float4(xj - 0.5f * wj, xj + 0.5f * wj,
                                             yj - 0.5f * hj, yj + 0.5f * hj);
            sh_aux[threadIdx.x] = make_float4(xj, yj, wj * hj, valid[j]);
        } else {
            sh_box[threadIdx.x] = make_float4(0.f, 0.f, 0.f, 0.f);
            sh_aux[threadIdx.x] = make_float4(0.f, 0.f, 0.f, 0.f);  // valid=0 -> mask 0
        }
        __syncthreads();

        if (i < n) {
            int jcount = min(TILE, n - jbase);
            for (int t = 0; t < jcount; ++t) {
                float4 bx = sh_box[t];   // broadcast: all lanes same addr
                float4 ax = sh_aux[t];
                int j2 = jbase + t;

                float iw = fminf(ri, bx.y) - fmaxf(li, bx.x);
                float ih = fminf(ti, bx.w) - fmaxf(bi, bx.z);
                iw = fmaxf(iw, 0.f);
                ih = fmaxf(ih, 0.f);
                float inter = iw * ih;
                float uni   = ai + ax.z - inter + EPSf;
                float iou   = inter / uni;          // iou >= 0, IOU_MARGIN=0 -> pen = iou

                float m = (j2 > i) ? vi * ax.w : 0.f;

                float dx = xi - ax.x;
                float dy = yi - ax.y;
                float dist = sqrtf(fmaf(dx, dx, fmaf(dy, dy, EPSf)));
                float rp = fmaxf(RM - dist, 0.f);

                s_iou += iou * m;
                s_rep += rp * rp * m;
                s_msk += m;
            }
        }
        __syncthreads();
    }

    // Wave (64-lane) reduction.
    for (int off = 32; off > 0; off >>= 1) {
        s_iou += __shfl_down(s_iou, off);
        s_rep += __shfl_down(s_rep, off);
        s_msk += __shfl_down(s_msk, off);
    }

    __shared__ float red[3][4];
    int lane = threadIdx.x & 63;
    int wid  = threadIdx.x >> 6;
    if (lane == 0) {
        red[0][wid] = s_iou;
        red[1][wid] = s_rep;
        red[2][wid] = s_msk;
    }
    __syncthreads();
    if (threadIdx.x == 0) {
        double a = 0.0, b = 0.0, c = 0.0;
        for (int k = 0; k < 4; ++k) {
            a += (double)red[0][k];
            b += (double)red[1][k];
            c += (double)red[2][k];
        }
        atomicAdd(&ws[0], a);
        atomicAdd(&ws[1], b);
        atomicAdd(&ws[2], c);
    }
}

__global__ void ol_finalize(const double* __restrict__ ws, float* __restrict__ out) {
    const double WEIGHT = 0.5;   // WEIGHT * RAMP
    const double EPSd   = 1e-6;
    double denom = ws[2] + EPSd;
    out[0] = (float)(WEIGHT * ((ws[0] + ws[1]) / denom));
}

extern "C" void kernel_launch(void* const* d_in, const int* in_sizes, int n_in,
                              void* d_out, int out_size, void* d_ws, size_t ws_size,
                              hipStream_t stream) {
    const float* pos   = (const float*)d_in[0];
    const float* size  = (const float*)d_in[1];
    const float* valid = (const float*)d_in[2];
    float* out = (float*)d_out;
    double* ws = (double*)d_ws;
    int n = in_sizes[2];  // valid_mask length = N

    ol_init_ws<<<1, 1, 0, stream>>>(ws);
    dim3 grid((n + TILE - 1) / TILE, N_SPLIT);
    ol_pair_kernel<<<grid, TILE, 0, stream>>>(pos, size, valid, ws, n);
    ol_finalize<<<1, 1, 0, stream>>>(ws, out);
}

// Round 3
// 41.404 us; speedup vs baseline: 3.5964x; 3.5964x over previous
//
#include <hip/hip_runtime.h>

#define TILE 128

template<bool DIAG>
__device__ __forceinline__ void inner_loop(
    const float4* __restrict__ sh_box, const float4* __restrict__ sh_aux,
    int jcount, int tid,
    float li, float ri, float bi, float ti, float xi, float yi,
    float aie, float vi, float& s_iou, float& s_rep, float& s_msk)
{
    const float RM   = 0.06f;
    const float EPSf = 1e-6f;
    #pragma unroll 4
    for (int t = 0; t < jcount; ++t) {
        float4 bx = sh_box[t];   // l, r, b, t  (broadcast LDS read)
        float4 ax = sh_aux[t];   // x, y, area, valid

        float iw = fmaxf(fminf(ri, bx.y) - fmaxf(li, bx.x), 0.f);
        float ih = fmaxf(fminf(ti, bx.w) - fmaxf(bi, bx.z), 0.f);
        float inter = iw * ih;
        float uni   = (aie - inter) + ax.z;           // aie = area_i + EPS, uni >= EPS
        float iou   = inter * __builtin_amdgcn_rcpf(uni);

        float m = vi * ax.w;
        if (DIAG) m = (t > tid) ? m : 0.f;            // j > i on the diagonal tile

        float dx = xi - ax.x;
        float dy = yi - ax.y;
        float d2 = fmaf(dx, dx, fmaf(dy, dy, EPSf));
        float dist = __builtin_amdgcn_sqrtf(d2);
        float rp = fmaxf(RM - dist, 0.f);

        s_iou = fmaf(iou, m, s_iou);
        s_rep = fmaf(rp * rp, m, s_rep);
        s_msk += m;
    }
}

__global__ __launch_bounds__(128) void ol_pair_kernel(
    const float* __restrict__ pos, const float* __restrict__ size,
    const float* __restrict__ valid, double* __restrict__ part,
    int n, int T, int P)
{
    __shared__ float4 sh_box[TILE];
    __shared__ float4 sh_aux[TILE];

    const float EPSf = 1e-6f;
    int tid = (int)threadIdx.x;

    // Decode linear block id -> upper-triangular tile pair (it, jt), jt >= it.
    // offset(r) = r*(2T - r + 1)/2 pairs precede row r.
    int bid = (int)blockIdx.x;
    int it = (int)(((2.0 * T + 1.0) -
                    sqrt((2.0 * T + 1.0) * (2.0 * T + 1.0) - 8.0 * (double)bid)) * 0.5);
    if (it >= T) it = T - 1;
    if (it < 0) it = 0;
    while ((it + 1) * (2 * T - it) / 2 <= bid) ++it;              // offset(it+1) <= bid
    while (it > 0 && it * (2 * T - it + 1) / 2 > bid) --it;       // offset(it)   >  bid
    int jt = it + (bid - it * (2 * T - it + 1) / 2);

    int i     = it * TILE + tid;
    int jbase = jt * TILE;

    // Load this thread's i-box.
    float xi = 0.f, yi = 0.f, li = 0.f, ri = 0.f, bi = 0.f, ti = 0.f, aie = EPSf, vi = 0.f;
    if (i < n) {
        xi = pos[2 * i];
        yi = pos[2 * i + 1];
        float wi = size[2 * i];
        float hi = size[2 * i + 1];
        li = xi - 0.5f * wi;  ri = xi + 0.5f * wi;
        bi = yi - 0.5f * hi;  ti = yi + 0.5f * hi;
        aie = wi * hi + EPSf;
        vi = valid[i];
    }

    // Stage j-tile into LDS.
    int j = jbase + tid;
    if (j < n) {
        float xj = pos[2 * j];
        float yj = pos[2 * j + 1];
        float wj = size[2 * j];
        float hj = size[2 * j + 1];
        sh_box[tid] = make_float4(xj - 0.5f * wj, xj + 0.5f * wj,
                                  yj - 0.5f * hj, yj + 0.5f * hj);
        sh_aux[tid] = make_float4(xj, yj, wj * hj, valid[j]);
    } else {
        sh_box[tid] = make_float4(0.f, 0.f, 0.f, 0.f);
        sh_aux[tid] = make_float4(0.f, 0.f, 0.f, 0.f);  // valid=0 -> mask 0
    }
    __syncthreads();

    float s_iou = 0.f, s_rep = 0.f, s_msk = 0.f;
    int jcount = min(TILE, n - jbase);
    if (jcount > 0) {
        if (it == jt)
            inner_loop<true >(sh_box, sh_aux, jcount, tid, li, ri, bi, ti, xi, yi, aie, vi,
                              s_iou, s_rep, s_msk);
        else
            inner_loop<false>(sh_box, sh_aux, jcount, tid, li, ri, bi, ti, xi, yi, aie, vi,
                              s_iou, s_rep, s_msk);
    }

    // Wave (64-lane) reduction, then combine the block's 2 waves.
    for (int off = 32; off > 0; off >>= 1) {
        s_iou += __shfl_down(s_iou, off);
        s_rep += __shfl_down(s_rep, off);
        s_msk += __shfl_down(s_msk, off);
    }
    __shared__ float red[3][2];
    int lane = tid & 63;
    int wid  = tid >> 6;
    if (lane == 0) {
        red[0][wid] = s_iou;
        red[1][wid] = s_rep;
        red[2][wid] = s_msk;
    }
    __syncthreads();
    if (tid == 0) {
        part[bid]         = (double)red[0][0] + (double)red[0][1];
        part[P + bid]     = (double)red[1][0] + (double)red[1][1];
        part[2 * P + bid] = (double)red[2][0] + (double)red[2][1];
    }
}

__global__ __launch_bounds__(256) void ol_finalize(
    const double* __restrict__ part, int P, float* __restrict__ out)
{
    double a = 0.0, b = 0.0, c = 0.0;
    for (int k = (int)threadIdx.x; k < P; k += 256) {
        a += part[k];
        b += part[P + k];
        c += part[2 * P + k];
    }
    __shared__ double sa[256], sb[256], sc[256];
    sa[threadIdx.x] = a; sb[threadIdx.x] = b; sc[threadIdx.x] = c;
    __syncthreads();
    for (int s = 128; s > 0; s >>= 1) {
        if ((int)threadIdx.x < s) {
            sa[threadIdx.x] += sa[threadIdx.x + s];
            sb[threadIdx.x] += sb[threadIdx.x + s];
            sc[threadIdx.x] += sc[threadIdx.x + s];
        }
        __syncthreads();
    }
    if (threadIdx.x == 0) {
        double denom = sc[0] + 1e-6;
        out[0] = (float)(0.5 * ((sa[0] + sb[0]) / denom));  // WEIGHT * RAMP = 0.5
    }
}

extern "C" void kernel_launch(void* const* d_in, const int* in_sizes, int n_in,
                              void* d_out, int out_size, void* d_ws, size_t ws_size,
                              hipStream_t stream) {
    const float* pos   = (const float*)d_in[0];
    const float* size  = (const float*)d_in[1];
    const float* valid = (const float*)d_in[2];
    float* out = (float*)d_out;
    double* ws = (double*)d_ws;
    int n = in_sizes[2];                 // valid_mask length = N
    int T = (n + TILE - 1) / TILE;       // 64 tiles at N=8192
    int P = T * (T + 1) / 2;             // 2080 upper-triangular tile pairs

    ol_pair_kernel<<<P, TILE, 0, stream>>>(pos, size, valid, ws, n, T, P);
    ol_finalize<<<1, 256, 0, stream>>>(ws, P, out);
}